// Round 8
// baseline (249.394 us; speedup 1.0000x reference)
//
#include <hip/hip_runtime.h>
#include <math.h>

// CPC loss, MI355X. B=16 T=512 D=256, horizons {1,5,21}, 128 negatives, temp 0.07.
// ws: [0,4MB) az f16 | [4MB,+2MB) ani int8 | [6MB,+384KB) Wh f16 |
//     [6.375MB,+12MB) zp f16 | [18.375MB,+6MB) zpq int8 | [24.375MB,+96KB) pos f32
constexpr int Bc = 16, Tc = 512, Dc = 256, NNEGc = 128, BTc = Bc * Tc;
constexpr float TEMP_INV = 1.0f / 0.07f;
constexpr float QSCALE = TEMP_INV / (127.0f * 127.0f);
constexpr float NEG_INF = -3.0e38f;

typedef __attribute__((ext_vector_type(8))) short short8;
typedef __attribute__((ext_vector_type(4))) float f32x4;
typedef __attribute__((ext_vector_type(4))) _Float16 f16x4;
typedef __attribute__((ext_vector_type(2))) _Float16 h2;

struct HP { int L, N, kh; float scale; long long nxOff; };
struct HP3 { HP h[3]; };

__device__ inline unsigned packh2(float a, float b) {
    h2 p = {(_Float16)a, (_Float16)b};
    return __builtin_bit_cast(unsigned, p);
}
__device__ inline float dot2(unsigned a, unsigned b, float c) {
#if __has_builtin(__builtin_amdgcn_fdot2)
    return __builtin_amdgcn_fdot2(__builtin_bit_cast(h2, a), __builtin_bit_cast(h2, b), c, false);
#else
    h2 x = __builtin_bit_cast(h2, a), y = __builtin_bit_cast(h2, b);
    return c + (float)x.x * (float)y.x + (float)x.y * (float)y.y;
#endif
}
__device__ inline int sdot4(unsigned a, unsigned b, int c) {
#if __has_builtin(__builtin_amdgcn_sdot4)
    return __builtin_amdgcn_sdot4((int)a, (int)b, c, false);
#else
    c += (int)(char)(a) * (int)(char)(b);
    c += (int)(char)(a >> 8) * (int)(char)(b >> 8);
    c += (int)(char)(a >> 16) * (int)(char)(b >> 16);
    c += (int)(char)(a >> 24) * (int)(char)(b >> 24);
    return c;
#endif
}
__device__ inline unsigned q4i8(float a, float b, float c, float d) {
    int qa = (int)rintf(a * 127.0f), qb = (int)rintf(b * 127.0f);
    int qc = (int)rintf(c * 127.0f), qd = (int)rintf(d * 127.0f);
    return (qa & 0xff) | ((qb & 0xff) << 8) | ((qc & 0xff) << 16) | ((unsigned)qd << 24);
}

// Normalize all BT rows -> az (f16) + ani (int8); first 96 blocks convert W; zero out.
__global__ __launch_bounds__(256) void k_norm(const float* __restrict__ z,
                                              const float* __restrict__ preds,
                                              unsigned* __restrict__ az,
                                              unsigned* __restrict__ ani,
                                              unsigned* __restrict__ Wh,
                                              float* __restrict__ out) {
    if (blockIdx.x == 0 && threadIdx.x == 0) out[0] = 0.0f;
    if (blockIdx.x < 96) {
        int base = blockIdx.x * 2048 + threadIdx.x * 8;
        float4 w0 = reinterpret_cast<const float4*>(preds + base)[0];
        float4 w1 = reinterpret_cast<const float4*>(preds + base)[1];
        uint4 o;
        o.x = packh2(w0.x, w0.y); o.y = packh2(w0.z, w0.w);
        o.z = packh2(w1.x, w1.y); o.w = packh2(w1.z, w1.w);
        reinterpret_cast<uint4*>(Wh)[blockIdx.x * 256 + threadIdx.x] = o;
    }
    int wid = threadIdx.x >> 6, lane = threadIdx.x & 63;
    int row = blockIdx.x * 4 + wid;
    float4 v = reinterpret_cast<const float4*>(z)[row * 64 + lane];
    float s = v.x * v.x + v.y * v.y + v.z * v.z + v.w * v.w;
#pragma unroll
    for (int off = 32; off; off >>= 1) s += __shfl_xor(s, off, 64);
    float inv = 1.0f / fmaxf(sqrtf(s), 1e-12f);
    float a = v.x * inv, b = v.y * inv, c = v.z * inv, d = v.w * inv;
    reinterpret_cast<uint2*>(az)[row * 64 + lane] = make_uint2(packh2(a, b), packh2(c, d));
    ani[row * 64 + lane] = q4i8(a, b, c, d);
}

// LDS-tiled f16 MFMA GEMM, XOR-swizzled LDS. Block 64x64, K=256, 4 waves.
__global__ __launch_bounds__(256) void k_gemm(const unsigned* __restrict__ az,
                                              const unsigned* __restrict__ Wh,
                                              _Float16* __restrict__ zp) {
    __shared__ uint4 As[2048];
    __shared__ uint4 Bs[2048];
    int wave = threadIdx.x >> 6, lane = threadIdx.x & 63;
    int t = threadIdx.x;
    int m0 = blockIdx.x * 64, g0 = blockIdx.y * 64;
    const uint4* A4 = reinterpret_cast<const uint4*>(az) + (size_t)m0 * 32;
    const uint4* B4 = reinterpret_cast<const uint4*>(Wh) + (size_t)g0 * 32;
#pragma unroll
    for (int i = 0; i < 8; ++i) {
        int f = i * 256 + t;
        int r = f >> 5, c = f & 31;
        int sw = r * 32 + ((c ^ r) & 31);
        As[sw] = A4[f];
        Bs[sw] = B4[f];
    }
    __syncthreads();
    int mrow = lane & 15, kq = lane >> 4;
    f32x4 acc[4] = {f32x4{0,0,0,0}, f32x4{0,0,0,0}, f32x4{0,0,0,0}, f32x4{0,0,0,0}};
    int arow = wave * 16 + mrow;
#pragma unroll
    for (int kb = 0; kb < 8; ++kb) {
        int col = kb * 4 + kq;
        uint4 ua = As[arow * 32 + ((col ^ arow) & 31)];
        short8 a = __builtin_bit_cast(short8, ua);
#pragma unroll
        for (int nt = 0; nt < 4; ++nt) {
            int brow = nt * 16 + mrow;
            uint4 ub = Bs[brow * 32 + ((col ^ brow) & 31)];
            acc[nt] = __builtin_amdgcn_mfma_f32_16x16x32_f16(
                a, __builtin_bit_cast(short8, ub), acc[nt], 0, 0, 0);
        }
    }
#pragma unroll
    for (int nt = 0; nt < 4; ++nt) {
        int g = g0 + nt * 16 + mrow;
        int h = g >> 8, e = g & 255;
        _Float16* dst = zp + ((size_t)h * BTc + m0 + wave * 16 + kq * 4) * Dc + e;
#pragma unroll
        for (int r = 0; r < 4; ++r) dst[(size_t)r * Dc] = (_Float16)acc[nt][r];
    }
}

// One wave per (h,n): normalize z_pred row, emit int8 zpq row (dense by n) and
// precomputed positive logit pos[h][n]. All coalesced.
__global__ __launch_bounds__(256) void k_prep(const _Float16* __restrict__ zp,
                                              const unsigned* __restrict__ az,
                                              unsigned* __restrict__ zpq,
                                              float* __restrict__ pos,
                                              HP3 P) {
    HP hp = P.h[blockIdx.y];
    int wid = threadIdx.x >> 6, lane = threadIdx.x & 63;
    int n = blockIdx.x * 4 + wid;
    if (n >= hp.N) return;  // wave-uniform
    int b = n / hp.L, l = n - b * hp.L;
    int row = b * Tc + l;
    f16x4 hv = reinterpret_cast<const f16x4*>(zp)[((size_t)blockIdx.y * BTc + row) * 64 + lane];
    float4 v = make_float4((float)hv.x, (float)hv.y, (float)hv.z, (float)hv.w);
    float s = v.x * v.x + v.y * v.y + v.z * v.z + v.w * v.w;
#pragma unroll
    for (int off = 32; off; off >>= 1) s += __shfl_xor(s, off, 64);
    float inv = 1.0f / fmaxf(sqrtf(s), 1e-12f);
    v.x *= inv; v.y *= inv; v.z *= inv; v.w *= inv;
    zpq[((size_t)blockIdx.y * 8192 + n) * 64 + lane] = q4i8(v.x, v.y, v.z, v.w);
    uint2 pw = reinterpret_cast<const uint2*>(az)[(size_t)(row + hp.kh) * 64 + lane];
    float pd = dot2(pw.y, packh2(v.z, v.w), dot2(pw.x, packh2(v.x, v.y), 0.0f));
#pragma unroll
    for (int off = 32; off; off >>= 1) pd += __shfl_xor(pd, off, 64);
    if (lane == 0) pos[blockIdx.y * 8192 + n] = pd * TEMP_INV;
}

// Block = 4 waves = 2 rows x 2 half-rows (64 negatives per wave). Minimal
// pre-gather chain (nidx + 4 shuffles + 4 broadcast zpq loads), then ALL 16
// gather loads issued before compute. Per-wave (m,s); block merges + pos.
__global__ __launch_bounds__(256, 4) void k_loss(const unsigned* __restrict__ ani,
                                                 const unsigned* __restrict__ zpq,
                                                 const float* __restrict__ pos,
                                                 const int* __restrict__ nx_base,
                                                 float* __restrict__ out,
                                                 HP3 P) {
    HP hp = P.h[blockIdx.y];
    __shared__ float pm[4], ps[4];
    int wid = threadIdx.x >> 6, lane = threadIdx.x & 63;
    int q = lane >> 2, q4 = lane & 3;
    int rloc = wid >> 1, half = wid & 1;
    int n = blockIdx.x * 2 + rloc;
    float mm = NEG_INF, sl = 0.0f;
    if (n < hp.N) {
        int i = nx_base[hp.nxOff + (size_t)n * NNEGc + half * 64 + lane];
        int idxp[4];
#pragma unroll
        for (int p = 0; p < 4; ++p) idxp[p] = __shfl(i, p * 16 + q, 64);
        const uint4* zq4 = reinterpret_cast<const uint4*>(zpq) +
                           ((size_t)blockIdx.y * 8192 + n) * 16;
        uint4 zqv[4];
#pragma unroll
        for (int c = 0; c < 4; ++c) zqv[c] = zq4[c * 4 + q4];
        const uint4* ni4 = reinterpret_cast<const uint4*>(ani);
        uint4 gb[4][4];
#pragma unroll
        for (int p = 0; p < 4; ++p)
#pragma unroll
            for (int c = 0; c < 4; ++c)
                gb[p][c] = ni4[(size_t)idxp[p] * 16 + c * 4 + q4];
        float lg[4];
#pragma unroll
        for (int p = 0; p < 4; ++p) {
            int acc = 0;
#pragma unroll
            for (int c = 0; c < 4; ++c) {
                acc = sdot4(gb[p][c].x, zqv[c].x, acc);
                acc = sdot4(gb[p][c].y, zqv[c].y, acc);
                acc = sdot4(gb[p][c].z, zqv[c].z, acc);
                acc = sdot4(gb[p][c].w, zqv[c].w, acc);
            }
            acc += __shfl_xor(acc, 1, 64);
            acc += __shfl_xor(acc, 2, 64);
            lg[p] = (float)acc * QSCALE;
        }
        mm = fmaxf(fmaxf(lg[0], lg[1]), fmaxf(lg[2], lg[3]));
#pragma unroll
        for (int off = 32; off; off >>= 1) mm = fmaxf(mm, __shfl_xor(mm, off, 64));
#pragma unroll
        for (int p = 0; p < 4; ++p) sl += __expf(lg[p] - mm);
#pragma unroll
        for (int off = 32; off; off >>= 1) sl += __shfl_xor(sl, off, 64);
        sl *= 0.25f;  // each negative replicated over the 4 lanes of its quad
    }
    if (lane == 0) { pm[wid] = mm; ps[wid] = sl; }
    __syncthreads();
    if (threadIdx.x == 0) {
        float c = 0.0f;
#pragma unroll
        for (int r = 0; r < 2; ++r) {
            int nn = blockIdx.x * 2 + r;
            if (nn >= hp.N) continue;
            float m0 = pm[2 * r], s0 = ps[2 * r];
            float m1 = pm[2 * r + 1], s1 = ps[2 * r + 1];
            float M = fmaxf(m0, m1);
            float S = s0 * __expf(m0 - M) + s1 * __expf(m1 - M);
            float p = pos[blockIdx.y * 8192 + nn];
            float M2 = fmaxf(M, p);
            float S2 = S * __expf(M - M2) + __expf(p - M2);
            c += (M2 + __logf(S2) - p) * hp.scale;
        }
        atomicAdd(out, c);
    }
}

// Fallback (R7 monolithic k_loss) if ws_size is short.
__global__ __launch_bounds__(256, 4) void k_loss_mono(const unsigned* __restrict__ az,
                                                      const unsigned* __restrict__ ani,
                                                      const _Float16* __restrict__ zp_base,
                                                      const int* __restrict__ nx_base,
                                                      float* __restrict__ out,
                                                      HP3 P) {
    HP hp = P.h[blockIdx.y];
    __shared__ unsigned zq[4][64];
    __shared__ float partial[4];
    int wid = threadIdx.x >> 6, lane = threadIdx.x & 63;
    int q = lane >> 2, q4 = lane & 3;
    int n = blockIdx.x * 4 + wid;
    float contrib = 0.0f;
    if (n < hp.N) {
        int b = n / hp.L, l = n - b * hp.L;
        int row = b * Tc + l;
        f16x4 hv = reinterpret_cast<const f16x4*>(
                       zp_base + ((size_t)blockIdx.y * BTc + row) * Dc)[lane];
        float4 v = make_float4((float)hv.x, (float)hv.y, (float)hv.z, (float)hv.w);
        float s = v.x * v.x + v.y * v.y + v.z * v.z + v.w * v.w;
#pragma unroll
        for (int off = 32; off; off >>= 1) s += __shfl_xor(s, off, 64);
        float inv = 1.0f / fmaxf(sqrtf(s), 1e-12f);
        v.x *= inv; v.y *= inv; v.z *= inv; v.w *= inv;
        zq[wid][lane] = q4i8(v.x, v.y, v.z, v.w);
        unsigned u0 = packh2(v.x, v.y), u1 = packh2(v.z, v.w);
        uint2 pw = reinterpret_cast<const uint2*>(az + (size_t)(row + hp.kh) * 128)[lane];
        float pd = dot2(pw.y, u1, dot2(pw.x, u0, 0.0f));
#pragma unroll
        for (int off = 32; off; off >>= 1) pd += __shfl_xor(pd, off, 64);
        float pos = pd * TEMP_INV;
        const int* nx = nx_base + hp.nxOff + (size_t)n * NNEGc;
        int i1 = nx[lane], i2 = nx[lane + 64];
        int idxp[8];
#pragma unroll
        for (int p = 0; p < 8; ++p)
            idxp[p] = __shfl(p < 4 ? i1 : i2, (p & 3) * 16 + q, 64);
        uint4 zqv[4];
        const uint4* zl4 = reinterpret_cast<const uint4*>(zq[wid]);
#pragma unroll
        for (int c = 0; c < 4; ++c) zqv[c] = zl4[c * 4 + q4];
        const uint4* ni4 = reinterpret_cast<const uint4*>(ani);
        float lg[8];
#pragma unroll
        for (int p = 0; p < 8; ++p) {
            uint4 g0 = ni4[(size_t)idxp[p] * 16 + 0 * 4 + q4];
            uint4 g1 = ni4[(size_t)idxp[p] * 16 + 1 * 4 + q4];
            uint4 g2 = ni4[(size_t)idxp[p] * 16 + 2 * 4 + q4];
            uint4 g3 = ni4[(size_t)idxp[p] * 16 + 3 * 4 + q4];
            int acc = 0;
            acc = sdot4(g0.x, zqv[0].x, acc); acc = sdot4(g0.y, zqv[0].y, acc);
            acc = sdot4(g0.z, zqv[0].z, acc); acc = sdot4(g0.w, zqv[0].w, acc);
            acc = sdot4(g1.x, zqv[1].x, acc); acc = sdot4(g1.y, zqv[1].y, acc);
            acc = sdot4(g1.z, zqv[1].z, acc); acc = sdot4(g1.w, zqv[1].w, acc);
            acc = sdot4(g2.x, zqv[2].x, acc); acc = sdot4(g2.y, zqv[2].y, acc);
            acc = sdot4(g2.z, zqv[2].z, acc); acc = sdot4(g2.w, zqv[2].w, acc);
            acc = sdot4(g3.x, zqv[3].x, acc); acc = sdot4(g3.y, zqv[3].y, acc);
            acc = sdot4(g3.w, zqv[3].w, acc); acc = sdot4(g3.z, zqv[3].z, acc);
            acc += __shfl_xor(acc, 1, 64);
            acc += __shfl_xor(acc, 2, 64);
            lg[p] = (float)acc * QSCALE;
        }
        float mm = lg[0];
#pragma unroll
        for (int p = 1; p < 8; ++p) mm = fmaxf(mm, lg[p]);
#pragma unroll
        for (int off = 32; off; off >>= 1) mm = fmaxf(mm, __shfl_xor(mm, off, 64));
        mm = fmaxf(mm, pos);
        float sl = 0.0f;
#pragma unroll
        for (int p = 0; p < 8; ++p) sl += __expf(lg[p] - mm);
#pragma unroll
        for (int off = 32; off; off >>= 1) sl += __shfl_xor(sl, off, 64);
        float S = sl * 0.25f + __expf(pos - mm);
        contrib = (mm + __logf(S) - pos) * hp.scale;
    }
    if (lane == 0) partial[wid] = contrib;
    __syncthreads();
    if (threadIdx.x == 0)
        atomicAdd(out, partial[0] + partial[1] + partial[2] + partial[3]);
}

extern "C" void kernel_launch(void* const* d_in, const int* in_sizes, int n_in,
                              void* d_out, int out_size, void* d_ws, size_t ws_size,
                              hipStream_t stream) {
    const float* z     = (const float*)d_in[0];
    const float* preds = (const float*)d_in[1];
    const int*   nidx  = (const int*)d_in[2];
    float* out = (float*)d_out;

    unsigned* az  = (unsigned*)d_ws;                                 // 4 MB
    unsigned* ani = (unsigned*)((char*)d_ws + (size_t)4194304);      // 2 MB
    unsigned* Wh  = (unsigned*)((char*)d_ws + (size_t)6291456);      // 384 KB
    _Float16* zp  = (_Float16*)((char*)d_ws + (size_t)6684672);      // 12 MB
    unsigned* zpq = (unsigned*)((char*)d_ws + (size_t)19267584);     // 6 MB
    float*    pos = (float*)((char*)d_ws + (size_t)25559040);        // 96 KB
    const size_t NEED = 25657344;

    const int ks[3] = {1, 5, 21};
    double rw[3] = {1.0, 1.0 / sqrt(5.0), 1.0 / sqrt(21.0)};
    double tot = rw[0] + rw[1] + rw[2];

    HP3 P;
    int maxN = 0;
    for (int i = 0; i < 3; ++i) {
        int L = Tc - ks[i], N = Bc * L;
        P.h[i].L = L; P.h[i].N = N; P.h[i].kh = ks[i];
        P.h[i].scale = (float)(rw[i] / tot / (double)N);
        P.h[i].nxOff = (long long)i * BTc * NNEGc;
        if (N > maxN) maxN = N;
    }

    k_norm<<<BTc / 4, 256, 0, stream>>>(z, preds, az, ani, Wh, out);
    k_gemm<<<dim3(BTc / 64, (3 * Dc) / 64), 256, 0, stream>>>(az, Wh, zp);
    if (ws_size >= NEED) {
        k_prep<<<dim3(BTc / 4, 3), 256, 0, stream>>>(zp, az, zpq, pos, P);
        k_loss<<<dim3((maxN + 1) / 2, 3), 256, 0, stream>>>(ani, zpq, pos, nidx, out, P);
    } else {
        k_loss_mono<<<dim3((maxN + 3) / 4, 3), 256, 0, stream>>>(az, ani, zp, nidx, out, P);
    }
}

// Round 9
// 121.931 us; speedup vs baseline: 2.0454x; 2.0454x over previous
//
#include <hip/hip_runtime.h>
#include <math.h>

// CPC loss, MI355X. B=16 T=512 D=256, horizons {1,5,21}, 128 negatives, temp 0.07.
// ws: [0,4MB) az f16 | [4MB,+2MB) ani int8 | [6MB,+384KB) Wh f16 |
//     [6.375MB,+12MB) zp f16 | [18.375MB,+24KB) partials f32
constexpr int Bc = 16, Tc = 512, Dc = 256, NNEGc = 128, BTc = Bc * Tc;
constexpr float TEMP_INV = 1.0f / 0.07f;
constexpr float QSCALE = TEMP_INV / (127.0f * 127.0f);
constexpr int GX = 2043;            // k_loss grid.x = ceil(8176/4)
constexpr int NPART = 3 * GX;       // 6129 partials

typedef __attribute__((ext_vector_type(8))) short short8;
typedef __attribute__((ext_vector_type(4))) float f32x4;
typedef __attribute__((ext_vector_type(4))) _Float16 f16x4;
typedef __attribute__((ext_vector_type(2))) _Float16 h2;

struct HP { int L, N, kh; float scale; long long nxOff; };
struct HP3 { HP h[3]; };

__device__ inline unsigned packh2(float a, float b) {
    h2 p = {(_Float16)a, (_Float16)b};
    return __builtin_bit_cast(unsigned, p);
}
__device__ inline float dot2(unsigned a, unsigned b, float c) {
#if __has_builtin(__builtin_amdgcn_fdot2)
    return __builtin_amdgcn_fdot2(__builtin_bit_cast(h2, a), __builtin_bit_cast(h2, b), c, false);
#else
    h2 x = __builtin_bit_cast(h2, a), y = __builtin_bit_cast(h2, b);
    return c + (float)x.x * (float)y.x + (float)x.y * (float)y.y;
#endif
}
__device__ inline int sdot4(unsigned a, unsigned b, int c) {
#if __has_builtin(__builtin_amdgcn_sdot4)
    return __builtin_amdgcn_sdot4((int)a, (int)b, c, false);
#else
    c += (int)(char)(a) * (int)(char)(b);
    c += (int)(char)(a >> 8) * (int)(char)(b >> 8);
    c += (int)(char)(a >> 16) * (int)(char)(b >> 16);
    c += (int)(char)(a >> 24) * (int)(char)(b >> 24);
    return c;
#endif
}
__device__ inline unsigned q4i8(float a, float b, float c, float d) {
    int qa = (int)rintf(a * 127.0f), qb = (int)rintf(b * 127.0f);
    int qc = (int)rintf(c * 127.0f), qd = (int)rintf(d * 127.0f);
    return (qa & 0xff) | ((qb & 0xff) << 8) | ((qc & 0xff) << 16) | ((unsigned)qd << 24);
}

// Normalize all BT rows -> az (f16) + ani (int8); first 96 blocks convert W.
__global__ __launch_bounds__(256) void k_norm(const float* __restrict__ z,
                                              const float* __restrict__ preds,
                                              unsigned* __restrict__ az,
                                              unsigned* __restrict__ ani,
                                              unsigned* __restrict__ Wh) {
    if (blockIdx.x < 96) {
        int base = blockIdx.x * 2048 + threadIdx.x * 8;
        float4 w0 = reinterpret_cast<const float4*>(preds + base)[0];
        float4 w1 = reinterpret_cast<const float4*>(preds + base)[1];
        uint4 o;
        o.x = packh2(w0.x, w0.y); o.y = packh2(w0.z, w0.w);
        o.z = packh2(w1.x, w1.y); o.w = packh2(w1.z, w1.w);
        reinterpret_cast<uint4*>(Wh)[blockIdx.x * 256 + threadIdx.x] = o;
    }
    int wid = threadIdx.x >> 6, lane = threadIdx.x & 63;
    int row = blockIdx.x * 4 + wid;
    float4 v = reinterpret_cast<const float4*>(z)[row * 64 + lane];
    float s = v.x * v.x + v.y * v.y + v.z * v.z + v.w * v.w;
#pragma unroll
    for (int off = 32; off; off >>= 1) s += __shfl_xor(s, off, 64);
    float inv = 1.0f / fmaxf(sqrtf(s), 1e-12f);
    float a = v.x * inv, b = v.y * inv, c = v.z * inv, d = v.w * inv;
    reinterpret_cast<uint2*>(az)[row * 64 + lane] = make_uint2(packh2(a, b), packh2(c, d));
    ani[row * 64 + lane] = q4i8(a, b, c, d);
}

// LDS-tiled f16 MFMA GEMM, XOR-swizzled LDS. Block 64x64, K=256, 4 waves.
__global__ __launch_bounds__(256) void k_gemm(const unsigned* __restrict__ az,
                                              const unsigned* __restrict__ Wh,
                                              _Float16* __restrict__ zp) {
    __shared__ uint4 As[2048];
    __shared__ uint4 Bs[2048];
    int wave = threadIdx.x >> 6, lane = threadIdx.x & 63;
    int t = threadIdx.x;
    int m0 = blockIdx.x * 64, g0 = blockIdx.y * 64;
    const uint4* A4 = reinterpret_cast<const uint4*>(az) + (size_t)m0 * 32;
    const uint4* B4 = reinterpret_cast<const uint4*>(Wh) + (size_t)g0 * 32;
#pragma unroll
    for (int i = 0; i < 8; ++i) {
        int f = i * 256 + t;
        int r = f >> 5, c = f & 31;
        int sw = r * 32 + ((c ^ r) & 31);
        As[sw] = A4[f];
        Bs[sw] = B4[f];
    }
    __syncthreads();
    int mrow = lane & 15, kq = lane >> 4;
    f32x4 acc[4] = {f32x4{0,0,0,0}, f32x4{0,0,0,0}, f32x4{0,0,0,0}, f32x4{0,0,0,0}};
    int arow = wave * 16 + mrow;
#pragma unroll
    for (int kb = 0; kb < 8; ++kb) {
        int col = kb * 4 + kq;
        uint4 ua = As[arow * 32 + ((col ^ arow) & 31)];
        short8 a = __builtin_bit_cast(short8, ua);
#pragma unroll
        for (int nt = 0; nt < 4; ++nt) {
            int brow = nt * 16 + mrow;
            uint4 ub = Bs[brow * 32 + ((col ^ brow) & 31)];
            acc[nt] = __builtin_amdgcn_mfma_f32_16x16x32_f16(
                a, __builtin_bit_cast(short8, ub), acc[nt], 0, 0, 0);
        }
    }
#pragma unroll
    for (int nt = 0; nt < 4; ++nt) {
        int g = g0 + nt * 16 + mrow;
        int h = g >> 8, e = g & 255;
        _Float16* dst = zp + ((size_t)h * BTc + m0 + wave * 16 + kq * 4) * Dc + e;
#pragma unroll
        for (int r = 0; r < 4; ++r) dst[(size_t)r * Dc] = (_Float16)acc[nt][r];
    }
}

// R7 monolithic k_loss, but NO shared atomic: one plain store per block.
__global__ __launch_bounds__(256, 4) void k_loss(const unsigned* __restrict__ az,
                                                 const unsigned* __restrict__ ani,
                                                 const _Float16* __restrict__ zp_base,
                                                 const int* __restrict__ nx_base,
                                                 float* __restrict__ partials,
                                                 HP3 P) {
    HP hp = P.h[blockIdx.y];
    __shared__ unsigned zq[4][64];
    __shared__ float partial[4];
    int wid = threadIdx.x >> 6, lane = threadIdx.x & 63;
    int q = lane >> 2, q4 = lane & 3;
    int n = blockIdx.x * 4 + wid;
    float contrib = 0.0f;
    if (n < hp.N) {
        int b = n / hp.L, l = n - b * hp.L;
        int row = b * Tc + l;
        f16x4 hv = reinterpret_cast<const f16x4*>(
                       zp_base + ((size_t)blockIdx.y * BTc + row) * Dc)[lane];
        float4 v = make_float4((float)hv.x, (float)hv.y, (float)hv.z, (float)hv.w);
        float s = v.x * v.x + v.y * v.y + v.z * v.z + v.w * v.w;
#pragma unroll
        for (int off = 32; off; off >>= 1) s += __shfl_xor(s, off, 64);
        float inv = 1.0f / fmaxf(sqrtf(s), 1e-12f);
        v.x *= inv; v.y *= inv; v.z *= inv; v.w *= inv;
        zq[wid][lane] = q4i8(v.x, v.y, v.z, v.w);
        unsigned u0 = packh2(v.x, v.y), u1 = packh2(v.z, v.w);
        uint2 pw = reinterpret_cast<const uint2*>(az + (size_t)(row + hp.kh) * 128)[lane];
        float pd = dot2(pw.y, u1, dot2(pw.x, u0, 0.0f));
#pragma unroll
        for (int off = 32; off; off >>= 1) pd += __shfl_xor(pd, off, 64);
        float pos = pd * TEMP_INV;
        const int* nx = nx_base + hp.nxOff + (size_t)n * NNEGc;
        int i1 = nx[lane], i2 = nx[lane + 64];
        int idxp[8];
#pragma unroll
        for (int p = 0; p < 8; ++p)
            idxp[p] = __shfl(p < 4 ? i1 : i2, (p & 3) * 16 + q, 64);
        uint4 zqv[4];
        const uint4* zl4 = reinterpret_cast<const uint4*>(zq[wid]);
#pragma unroll
        for (int c = 0; c < 4; ++c) zqv[c] = zl4[c * 4 + q4];
        const uint4* ni4 = reinterpret_cast<const uint4*>(ani);
        float lg[8];
#pragma unroll
        for (int p = 0; p < 8; ++p) {
            uint4 g0 = ni4[(size_t)idxp[p] * 16 + 0 * 4 + q4];
            uint4 g1 = ni4[(size_t)idxp[p] * 16 + 1 * 4 + q4];
            uint4 g2 = ni4[(size_t)idxp[p] * 16 + 2 * 4 + q4];
            uint4 g3 = ni4[(size_t)idxp[p] * 16 + 3 * 4 + q4];
            int acc = 0;
            acc = sdot4(g0.x, zqv[0].x, acc); acc = sdot4(g0.y, zqv[0].y, acc);
            acc = sdot4(g0.z, zqv[0].z, acc); acc = sdot4(g0.w, zqv[0].w, acc);
            acc = sdot4(g1.x, zqv[1].x, acc); acc = sdot4(g1.y, zqv[1].y, acc);
            acc = sdot4(g1.z, zqv[1].z, acc); acc = sdot4(g1.w, zqv[1].w, acc);
            acc = sdot4(g2.x, zqv[2].x, acc); acc = sdot4(g2.y, zqv[2].y, acc);
            acc = sdot4(g2.z, zqv[2].z, acc); acc = sdot4(g2.w, zqv[2].w, acc);
            acc = sdot4(g3.x, zqv[3].x, acc); acc = sdot4(g3.y, zqv[3].y, acc);
            acc = sdot4(g3.z, zqv[3].z, acc); acc = sdot4(g3.w, zqv[3].w, acc);
            acc += __shfl_xor(acc, 1, 64);
            acc += __shfl_xor(acc, 2, 64);
            lg[p] = (float)acc * QSCALE;
        }
        float mm = lg[0];
#pragma unroll
        for (int p = 1; p < 8; ++p) mm = fmaxf(mm, lg[p]);
#pragma unroll
        for (int off = 32; off; off >>= 1) mm = fmaxf(mm, __shfl_xor(mm, off, 64));
        mm = fmaxf(mm, pos);
        float sl = 0.0f;
#pragma unroll
        for (int p = 0; p < 8; ++p) sl += __expf(lg[p] - mm);
#pragma unroll
        for (int off = 32; off; off >>= 1) sl += __shfl_xor(sl, off, 64);
        float S = sl * 0.25f + __expf(pos - mm);
        contrib = (mm + __logf(S) - pos) * hp.scale;
    }
    if (lane == 0) partial[wid] = contrib;
    __syncthreads();
    if (threadIdx.x == 0)
        partials[blockIdx.y * GX + blockIdx.x] =
            partial[0] + partial[1] + partial[2] + partial[3];
}

// Single-block deterministic reduction of NPART partials -> out[0].
__global__ __launch_bounds__(256) void k_final(const float* __restrict__ partials,
                                               float* __restrict__ out) {
    __shared__ float ws[4];
    int wid = threadIdx.x >> 6, lane = threadIdx.x & 63;
    float s = 0.0f;
    for (int i = threadIdx.x; i < NPART; i += 256) s += partials[i];
#pragma unroll
    for (int off = 32; off; off >>= 1) s += __shfl_xor(s, off, 64);
    if (lane == 0) ws[wid] = s;
    __syncthreads();
    if (threadIdx.x == 0) out[0] = ws[0] + ws[1] + ws[2] + ws[3];
}

extern "C" void kernel_launch(void* const* d_in, const int* in_sizes, int n_in,
                              void* d_out, int out_size, void* d_ws, size_t ws_size,
                              hipStream_t stream) {
    const float* z     = (const float*)d_in[0];
    const float* preds = (const float*)d_in[1];
    const int*   nidx  = (const int*)d_in[2];
    float* out = (float*)d_out;

    unsigned* az   = (unsigned*)d_ws;                                // 4 MB
    unsigned* ani  = (unsigned*)((char*)d_ws + (size_t)4194304);     // 2 MB
    unsigned* Wh   = (unsigned*)((char*)d_ws + (size_t)6291456);     // 384 KB
    _Float16* zp   = (_Float16*)((char*)d_ws + (size_t)6684672);     // 12 MB
    float*    part = (float*)((char*)d_ws + (size_t)19267584);       // 24 KB

    const int ks[3] = {1, 5, 21};
    double rw[3] = {1.0, 1.0 / sqrt(5.0), 1.0 / sqrt(21.0)};
    double tot = rw[0] + rw[1] + rw[2];

    HP3 P;
    for (int i = 0; i < 3; ++i) {
        int L = Tc - ks[i], N = Bc * L;
        P.h[i].L = L; P.h[i].N = N; P.h[i].kh = ks[i];
        P.h[i].scale = (float)(rw[i] / tot / (double)N);
        P.h[i].nxOff = (long long)i * BTc * NNEGc;
    }

    k_norm<<<BTc / 4, 256, 0, stream>>>(z, preds, az, ani, Wh);
    k_gemm<<<dim3(BTc / 64, (3 * Dc) / 64), 256, 0, stream>>>(az, Wh, zp);
    k_loss<<<dim3(GX, 3), 256, 0, stream>>>(az, ani, zp, nidx, part, P);
    k_final<<<1, 256, 0, stream>>>(part, out);
}